// Round 1
// baseline (124544.690 us; speedup 1.0000x reference)
//
#include <hip/hip_runtime.h>
#include <hip/hip_bf16.h>
#include <cstddef>

// Problem constants
constexpr int T = 8192;   // SEQ_LEN
constexpr int H = 1024;   // NHID == NIN
constexpr int N3 = 3 * H; // 3072
constexpr int G = 128;    // persistent scan blocks (<= 256 CUs, cooperative)

// ---------------------------------------------------------------------------
// Kernel 1: x_proj = xs @ w_ih.T + b   (M=8192, N=3072, K=1024, fp32)
// Simple LDS-tiled GEMM. BM=BN=64, BK=16, 256 threads, 4x4 micro-tile.
// Row pad of 20 floats (80B) keeps float4 alignment and breaks pow2 bank stride.
// ---------------------------------------------------------------------------
#define BM 64
#define BN 64
#define BK 16
#define PAD 20

__global__ __launch_bounds__(256) void xproj_gemm(const float* __restrict__ A,   // xs [M,K]
                                                  const float* __restrict__ W,   // w_ih [N,K]
                                                  const float* __restrict__ bias,
                                                  float* __restrict__ C) {      // [M,N]
  __shared__ float As[BM * PAD];
  __shared__ float Bs[BN * PAD];
  const int tid = threadIdx.x;
  const int tx = tid & 15;   // N dir
  const int ty = tid >> 4;   // M dir
  const int m0 = blockIdx.y * BM;
  const int n0 = blockIdx.x * BN;

  const int lr = tid >> 2;        // 0..63 row to load
  const int lc = (tid & 3) * 4;   // col offset (float4)

  float acc[4][4] = {};

  for (int k0 = 0; k0 < H; k0 += BK) {
    float4 av = *(const float4*)&A[(size_t)(m0 + lr) * H + k0 + lc];
    float4 bv = *(const float4*)&W[(size_t)(n0 + lr) * H + k0 + lc];
    *(float4*)&As[lr * PAD + lc] = av;
    *(float4*)&Bs[lr * PAD + lc] = bv;
    __syncthreads();
#pragma unroll
    for (int kk = 0; kk < BK; kk += 4) {
      float4 a[4], b[4];
#pragma unroll
      for (int i = 0; i < 4; ++i) a[i] = *(const float4*)&As[(ty * 4 + i) * PAD + kk];
#pragma unroll
      for (int j = 0; j < 4; ++j) b[j] = *(const float4*)&Bs[(tx * 4 + j) * PAD + kk];
#pragma unroll
      for (int i = 0; i < 4; ++i)
#pragma unroll
        for (int j = 0; j < 4; ++j)
          acc[i][j] += a[i].x * b[j].x + a[i].y * b[j].y + a[i].z * b[j].z + a[i].w * b[j].w;
    }
    __syncthreads();
  }

  float4 bb = *(const float4*)&bias[n0 + tx * 4];
#pragma unroll
  for (int i = 0; i < 4; ++i) {
    float4 o;
    o.x = acc[i][0] + bb.x;
    o.y = acc[i][1] + bb.y;
    o.z = acc[i][2] + bb.z;
    o.w = acc[i][3] + bb.w;
    *(float4*)&C[(size_t)(m0 + ty * 4 + i) * N3 + n0 + tx * 4] = o;
  }
}

// ---------------------------------------------------------------------------
// Kernel 2: persistent GRU scan.
// 128 blocks x 256 threads (4 waves). Each wave owns 2 hidden units (x3 gates
// = 6 rows of w_hh). Weights live in registers: 6 rows x 16 elems = 96 VGPRs
// per thread (lane l holds elements k = j*64 + l). Per step:
//   load h (16 agent loads) -> 96 reg FMAs -> butterfly reduce (all lanes get
//   all 6 sums) -> lanes 0/1 compute gates for their unit -> store h_new ->
//   grid barrier (sense = step counter, agent-scope atomics).
// ---------------------------------------------------------------------------
__device__ __forceinline__ float sigmoidf_fast(float x) {
  return 1.0f / (1.0f + __expf(-x));
}
__device__ __forceinline__ float tanhf_fast(float x) {
  float ax = fabsf(x);
  float e = __expf(-2.0f * ax);      // e <= 1, always stable
  float t = (1.0f - e) / (1.0f + e);
  return copysignf(t, x);
}

__global__ __launch_bounds__(256, 1) void gru_scan(const float* __restrict__ xp,
                                                   const float* __restrict__ whh,
                                                   const float* __restrict__ bn,
                                                   float* __restrict__ hbuf,   // 2*H floats
                                                   unsigned* __restrict__ bar, // cnt, sense
                                                   float* __restrict__ out) {  // 2*T*H floats
  const int tid = threadIdx.x;
  const int w = tid >> 6;
  const int l = tid & 63;
  const int ublk = blockIdx.x * 8 + 2 * w;  // first of this wave's 2 units

  // Load w_hh into registers. Row for r6: gate g = r6>>1, unit = ublk + (r6&1).
  float wreg[6][16];
#pragma unroll
  for (int r6 = 0; r6 < 6; ++r6) {
    const int g = r6 >> 1;
    const int u = ublk + (r6 & 1);
    const float* wrow = whh + (size_t)(g * H + u) * H;
#pragma unroll
    for (int j = 0; j < 16; ++j) wreg[r6][j] = wrow[j * 64 + l];
  }

  const int myu = ublk + l;                       // meaningful for l < 2
  const float bnv = (l < 2) ? bn[myu] : 0.0f;

  unsigned* cnt = bar;
  unsigned* sense = bar + 1;

#pragma unroll 1
  for (int t = 0; t < T; ++t) {
    const float* hb = hbuf + (t & 1) * H;
    float* hn = hbuf + ((t + 1) & 1) * H;

    // Prefetch per-unit inputs early (independent of h FMAs).
    float ir = 0.f, iz = 0.f, ig = 0.f, hold = 0.f;
    if (l < 2) {
      const float* xpt = xp + (size_t)t * N3;
      ir = xpt[myu];
      iz = xpt[H + myu];
      ig = xpt[2 * H + myu];
      hold = __hip_atomic_load(hb + myu, __ATOMIC_RELAXED, __HIP_MEMORY_SCOPE_AGENT);
    }

    float hv[16];
#pragma unroll
    for (int j = 0; j < 16; ++j)
      hv[j] = __hip_atomic_load(hb + j * 64 + l, __ATOMIC_RELAXED, __HIP_MEMORY_SCOPE_AGENT);

    float acc[6] = {0.f, 0.f, 0.f, 0.f, 0.f, 0.f};
#pragma unroll
    for (int j = 0; j < 16; ++j) {
#pragma unroll
      for (int r6 = 0; r6 < 6; ++r6) acc[r6] += wreg[r6][j] * hv[j];
    }

    // Butterfly reduction over 64 lanes; every lane ends with all 6 sums.
#pragma unroll
    for (int off = 32; off >= 1; off >>= 1) {
#pragma unroll
      for (int r6 = 0; r6 < 6; ++r6) acc[r6] += __shfl_xor(acc[r6], off, 64);
    }

    if (l < 2) {
      // lane l handles unit ublk+l: hr=acc[l], hz=acc[2+l], hg=acc[4+l]
      float r = sigmoidf_fast(ir + acc[l]);
      float z = sigmoidf_fast(iz + acc[2 + l]);
      float gg = tanhf_fast(ig + r * (acc[4 + l] + bnv));
      float hnew = (1.0f - z) * gg + z * hold;
      __hip_atomic_store(hn + myu, hnew, __ATOMIC_RELAXED, __HIP_MEMORY_SCOPE_AGENT);
      out[(size_t)t * H + myu] = hnew;
      out[(size_t)T * H + (size_t)t * H + myu] = hnew;  // second tuple copy
    }

    // ---- grid barrier (sense-reversing, monotonically increasing sense) ----
    __syncthreads();
    if (tid == 0) {
      __threadfence();  // publish this block's stores (device scope)
      unsigned arrived =
          __hip_atomic_fetch_add(cnt, 1u, __ATOMIC_ACQ_REL, __HIP_MEMORY_SCOPE_AGENT);
      if (arrived == G - 1) {
        __hip_atomic_store(cnt, 0u, __ATOMIC_RELAXED, __HIP_MEMORY_SCOPE_AGENT);
        __hip_atomic_store(sense, (unsigned)(t + 1), __ATOMIC_RELEASE,
                           __HIP_MEMORY_SCOPE_AGENT);
      } else {
        while (__hip_atomic_load(sense, __ATOMIC_ACQUIRE, __HIP_MEMORY_SCOPE_AGENT) <
               (unsigned)(t + 1)) {
        }
      }
      __threadfence();  // acquire side: invalidate stale cached h
    }
    __syncthreads();
  }
}

// ---------------------------------------------------------------------------
extern "C" void kernel_launch(void* const* d_in, const int* in_sizes, int n_in,
                              void* d_out, int out_size, void* d_ws, size_t ws_size,
                              hipStream_t stream) {
  const float* xs   = (const float*)d_in[0];
  const float* w_ih = (const float*)d_in[1];
  const float* w_hh = (const float*)d_in[2];
  const float* b    = (const float*)d_in[3];
  const float* bn   = (const float*)d_in[4];
  float* out = (float*)d_out;

  // Workspace layout: x_proj (T*3H fp32 = 96MB) | hbuf (2*H) | barrier (2 u32)
  float* xp = (float*)d_ws;
  float* hbuf = xp + (size_t)T * N3;
  unsigned* bar = (unsigned*)(hbuf + 2 * H);

  // zero h0 (both buffers) + barrier state; re-done every call (deterministic)
  hipMemsetAsync(hbuf, 0, 2 * H * sizeof(float) + 2 * sizeof(unsigned), stream);

  dim3 ggrid(N3 / BN, T / BM);
  xproj_gemm<<<ggrid, 256, 0, stream>>>(xs, w_ih, b, xp);

  void* args[] = {(void*)&xp, (void*)&w_hh, (void*)&bn, (void*)&hbuf, (void*)&bar, (void*)&out};
  hipLaunchCooperativeKernel((void*)gru_scan, dim3(G), dim3(256), args, 0, stream);
}

// Round 2
// 56424.414 us; speedup vs baseline: 2.2073x; 2.2073x over previous
//
#include <hip/hip_runtime.h>
#include <hip/hip_bf16.h>
#include <cstddef>

// Problem constants
constexpr int T = 8192;   // SEQ_LEN
constexpr int H = 1024;   // NHID == NIN
constexpr int N3 = 3 * H; // 3072
constexpr int G = 128;    // persistent scan blocks (cooperative, 1/2 of CUs)

// ---------------------------------------------------------------------------
// Kernel 1: x_proj = xs @ w_ih.T + b   (M=8192, N=3072, K=1024, fp32)
// ---------------------------------------------------------------------------
#define BM 64
#define BN 64
#define BK 16
#define PAD 20

__global__ __launch_bounds__(256) void xproj_gemm(const float* __restrict__ A,   // xs [M,K]
                                                  const float* __restrict__ W,   // w_ih [N,K]
                                                  const float* __restrict__ bias,
                                                  float* __restrict__ C) {      // [M,N]
  __shared__ float As[BM * PAD];
  __shared__ float Bs[BN * PAD];
  const int tid = threadIdx.x;
  const int tx = tid & 15;   // N dir
  const int ty = tid >> 4;   // M dir
  const int m0 = blockIdx.y * BM;
  const int n0 = blockIdx.x * BN;

  const int lr = tid >> 2;        // 0..63 row to load
  const int lc = (tid & 3) * 4;   // col offset (float4)

  float acc[4][4] = {};

  for (int k0 = 0; k0 < H; k0 += BK) {
    float4 av = *(const float4*)&A[(size_t)(m0 + lr) * H + k0 + lc];
    float4 bv = *(const float4*)&W[(size_t)(n0 + lr) * H + k0 + lc];
    *(float4*)&As[lr * PAD + lc] = av;
    *(float4*)&Bs[lr * PAD + lc] = bv;
    __syncthreads();
#pragma unroll
    for (int kk = 0; kk < BK; kk += 4) {
      float4 a[4], b[4];
#pragma unroll
      for (int i = 0; i < 4; ++i) a[i] = *(const float4*)&As[(ty * 4 + i) * PAD + kk];
#pragma unroll
      for (int j = 0; j < 4; ++j) b[j] = *(const float4*)&Bs[(tx * 4 + j) * PAD + kk];
#pragma unroll
      for (int i = 0; i < 4; ++i)
#pragma unroll
        for (int j = 0; j < 4; ++j)
          acc[i][j] += a[i].x * b[j].x + a[i].y * b[j].y + a[i].z * b[j].z + a[i].w * b[j].w;
    }
    __syncthreads();
  }

  float4 bb = *(const float4*)&bias[n0 + tx * 4];
#pragma unroll
  for (int i = 0; i < 4; ++i) {
    float4 o;
    o.x = acc[i][0] + bb.x;
    o.y = acc[i][1] + bb.y;
    o.z = acc[i][2] + bb.z;
    o.w = acc[i][3] + bb.w;
    *(float4*)&C[(size_t)(m0 + ty * 4 + i) * N3 + n0 + tx * 4] = o;
  }
}

// ---------------------------------------------------------------------------
// Kernel 2: persistent GRU scan — BARRIER-FREE dataflow sync.
//
// Each h element is a 64-bit word {hi: tag = step index, lo: float value},
// written with ONE relaxed agent-scope 8B atomic store (tag+value atomic,
// so no fences / release chains are needed). Consumers poll per element:
// issue all 16 loads (pipelined), then re-poll only the stale ones.
//
// Double-buffer safety without a barrier: a producer writes h_{t+2} over the
// h_t slot only after reading ALL of h_{t+1} (tags >= t+1), which implies
// every wave already finished step t and no longer reads h_t.
//
// Waves are fully independent actors (no __syncthreads at all): each wave
// owns 2 hidden units (6 w_hh rows in 96 VGPRs, lane l holds k = j*64+l).
// ---------------------------------------------------------------------------
__device__ __forceinline__ float sigmoidf_fast(float x) {
  return 1.0f / (1.0f + __expf(-x));
}
__device__ __forceinline__ float tanhf_fast(float x) {
  float ax = fabsf(x);
  float e = __expf(-2.0f * ax);      // e <= 1, always stable
  float t = (1.0f - e) / (1.0f + e);
  return copysignf(t, x);
}

__global__ __launch_bounds__(256, 1) void gru_scan(const float* __restrict__ xp,
                                                   const float* __restrict__ whh,
                                                   const float* __restrict__ bn,
                                                   unsigned long long* __restrict__ hbuf, // 2*H tagged
                                                   float* __restrict__ out) {  // 2*T*H floats
  const int tid = threadIdx.x;
  const int w = tid >> 6;
  const int l = tid & 63;
  const int ublk = blockIdx.x * 8 + 2 * w;  // first of this wave's 2 units

  // Load w_hh into registers. Row r6: gate g = r6>>1, unit = ublk + (r6&1).
  float wreg[6][16];
#pragma unroll
  for (int r6 = 0; r6 < 6; ++r6) {
    const int g = r6 >> 1;
    const int u = ublk + (r6 & 1);
    const float* wrow = whh + (size_t)(g * H + u) * H;
#pragma unroll
    for (int j = 0; j < 16; ++j) wreg[r6][j] = wrow[j * 64 + l];
  }

  const int myu = ublk + l;                       // meaningful for l < 2
  const float bnv = (l < 2) ? bn[myu] : 0.0f;

#pragma unroll 1
  for (int t = 0; t < T; ++t) {
    unsigned long long* hb = hbuf + (t & 1) * H;
    unsigned long long* hn = hbuf + ((t + 1) & 1) * H;

    // Early-issue per-unit inputs (off the critical path).
    float ir = 0.f, iz = 0.f, ig = 0.f;
    unsigned long long ph = ~0ull;  // inactive lanes: tag=0xFFFFFFFF, no poll
    if (l < 2) {
      const float* xpt = xp + (size_t)t * N3;
      ir = xpt[myu];
      iz = xpt[H + myu];
      ig = xpt[2 * H + myu];
      ph = __hip_atomic_load(hb + myu, __ATOMIC_RELAXED, __HIP_MEMORY_SCOPE_AGENT);
    }

    // Phase 1: issue all 16 h loads (one overlapped latency).
    unsigned long long pv[16];
#pragma unroll
    for (int j = 0; j < 16; ++j)
      pv[j] = __hip_atomic_load(hb + j * 64 + l, __ATOMIC_RELAXED, __HIP_MEMORY_SCOPE_AGENT);

    // Phase 2: re-poll only the stale elements.
#pragma unroll
    for (int j = 0; j < 16; ++j)
      while ((unsigned)(pv[j] >> 32) < (unsigned)t)
        pv[j] = __hip_atomic_load(hb + j * 64 + l, __ATOMIC_RELAXED, __HIP_MEMORY_SCOPE_AGENT);
    if (l < 2)
      while ((unsigned)(ph >> 32) < (unsigned)t)
        ph = __hip_atomic_load(hb + myu, __ATOMIC_RELAXED, __HIP_MEMORY_SCOPE_AGENT);

    float acc[6] = {0.f, 0.f, 0.f, 0.f, 0.f, 0.f};
#pragma unroll
    for (int j = 0; j < 16; ++j) {
      const float hvj = __uint_as_float((unsigned)pv[j]);
#pragma unroll
      for (int r6 = 0; r6 < 6; ++r6) acc[r6] += wreg[r6][j] * hvj;
    }

    // Butterfly reduction over 64 lanes; every lane ends with all 6 sums.
#pragma unroll
    for (int off = 32; off >= 1; off >>= 1) {
#pragma unroll
      for (int r6 = 0; r6 < 6; ++r6) acc[r6] += __shfl_xor(acc[r6], off, 64);
    }

    if (l < 2) {
      const float hold = __uint_as_float((unsigned)ph);
      // lane l handles unit ublk+l: hr=acc[l], hz=acc[2+l], hg=acc[4+l]
      float r = sigmoidf_fast(ir + acc[l]);
      float z = sigmoidf_fast(iz + acc[2 + l]);
      float gg = tanhf_fast(ig + r * (acc[4 + l] + bnv));
      float hnew = (1.0f - z) * gg + z * hold;
      unsigned long long pk =
          ((unsigned long long)(unsigned)(t + 1) << 32) |
          (unsigned long long)__float_as_uint(hnew);
      __hip_atomic_store(hn + myu, pk, __ATOMIC_RELAXED, __HIP_MEMORY_SCOPE_AGENT);
      out[(size_t)t * H + myu] = hnew;
      out[(size_t)T * H + (size_t)t * H + myu] = hnew;  // second tuple copy
    }
  }
}

// ---------------------------------------------------------------------------
extern "C" void kernel_launch(void* const* d_in, const int* in_sizes, int n_in,
                              void* d_out, int out_size, void* d_ws, size_t ws_size,
                              hipStream_t stream) {
  const float* xs   = (const float*)d_in[0];
  const float* w_ih = (const float*)d_in[1];
  const float* w_hh = (const float*)d_in[2];
  const float* b    = (const float*)d_in[3];
  const float* bn   = (const float*)d_in[4];
  float* out = (float*)d_out;

  // Workspace layout: x_proj (T*3H fp32 = 96MB) | tagged hbuf (2*H u64)
  float* xp = (float*)d_ws;
  unsigned long long* hbuf = (unsigned long long*)(xp + (size_t)T * N3);

  // h0 = 0 with tag 0 (matches step-0 poll); re-done every call inside graph.
  hipMemsetAsync(hbuf, 0, 2 * H * sizeof(unsigned long long), stream);

  dim3 ggrid(N3 / BN, T / BM);
  xproj_gemm<<<ggrid, 256, 0, stream>>>(xs, w_ih, b, xp);

  void* args[] = {(void*)&xp, (void*)&w_hh, (void*)&bn, (void*)&hbuf, (void*)&out};
  hipLaunchCooperativeKernel((void*)gru_scan, dim3(G), dim3(256), args, 0, stream);
}

// Round 3
// 31819.812 us; speedup vs baseline: 3.9141x; 1.7732x over previous
//
#include <hip/hip_runtime.h>
#include <hip/hip_bf16.h>
#include <cstddef>

// Problem constants
constexpr int T = 8192;   // SEQ_LEN
constexpr int H = 1024;   // NHID == NIN
constexpr int N3 = 3 * H; // 3072
constexpr int G = 128;    // persistent scan blocks (cooperative)

// ---------------------------------------------------------------------------
// Kernel 1: x_proj = xs @ w_ih.T + b   (M=8192, N=3072, K=1024, fp32)
// ---------------------------------------------------------------------------
#define BM 64
#define BN 64
#define BK 16
#define PAD 20

__global__ __launch_bounds__(256) void xproj_gemm(const float* __restrict__ A,   // xs [M,K]
                                                  const float* __restrict__ W,   // w_ih [N,K]
                                                  const float* __restrict__ bias,
                                                  float* __restrict__ C) {      // [M,N]
  __shared__ float As[BM * PAD];
  __shared__ float Bs[BN * PAD];
  const int tid = threadIdx.x;
  const int tx = tid & 15;   // N dir
  const int ty = tid >> 4;   // M dir
  const int m0 = blockIdx.y * BM;
  const int n0 = blockIdx.x * BN;

  const int lr = tid >> 2;        // 0..63 row to load
  const int lc = (tid & 3) * 4;   // col offset (float4)

  float acc[4][4] = {};

  for (int k0 = 0; k0 < H; k0 += BK) {
    float4 av = *(const float4*)&A[(size_t)(m0 + lr) * H + k0 + lc];
    float4 bv = *(const float4*)&W[(size_t)(n0 + lr) * H + k0 + lc];
    *(float4*)&As[lr * PAD + lc] = av;
    *(float4*)&Bs[lr * PAD + lc] = bv;
    __syncthreads();
#pragma unroll
    for (int kk = 0; kk < BK; kk += 4) {
      float4 a[4], b[4];
#pragma unroll
      for (int i = 0; i < 4; ++i) a[i] = *(const float4*)&As[(ty * 4 + i) * PAD + kk];
#pragma unroll
      for (int j = 0; j < 4; ++j) b[j] = *(const float4*)&Bs[(tx * 4 + j) * PAD + kk];
#pragma unroll
      for (int i = 0; i < 4; ++i)
#pragma unroll
        for (int j = 0; j < 4; ++j)
          acc[i][j] += a[i].x * b[j].x + a[i].y * b[j].y + a[i].z * b[j].z + a[i].w * b[j].w;
    }
    __syncthreads();
  }

  float4 bb = *(const float4*)&bias[n0 + tx * 4];
#pragma unroll
  for (int i = 0; i < 4; ++i) {
    float4 o;
    o.x = acc[i][0] + bb.x;
    o.y = acc[i][1] + bb.y;
    o.z = acc[i][2] + bb.z;
    o.w = acc[i][3] + bb.w;
    *(float4*)&C[(size_t)(m0 + ty * 4 + i) * N3 + n0 + tx * 4] = o;
  }
}

// ---------------------------------------------------------------------------
// Kernel 2: persistent GRU scan — barrier-free dataflow sync, BATCH poll.
//
// Each h element: 64-bit word {hi: tag = step+1, lo: fp32 value}, one relaxed
// agent-scope 8B atomic store. Consumers gather all 16 of their elements,
// then batch-re-poll: build stale mask -> reload ALL stale concurrently ->
// recheck -> while(__any(stale)). One LLC round trip per poll ROUND instead
// of one per stale ELEMENT (the R2 mistake: serial while-loops).
//
// Double-buffer safety without barriers: a producer overwrites the h_t slot
// (with h_{t+2}) only after reading all of h_{t+1}, which implies every wave
// finished step t and no longer reads h_t.
// ---------------------------------------------------------------------------
__device__ __forceinline__ float sigmoidf_fast(float x) {
  return 1.0f / (1.0f + __expf(-x));
}
__device__ __forceinline__ float tanhf_fast(float x) {
  float ax = fabsf(x);
  float e = __expf(-2.0f * ax);      // e <= 1, always stable
  float t = (1.0f - e) / (1.0f + e);
  return copysignf(t, x);
}

__global__ __launch_bounds__(256, 1) void gru_scan(const float* __restrict__ xp,
                                                   const float* __restrict__ whh,
                                                   const float* __restrict__ bn,
                                                   unsigned long long* __restrict__ hbuf, // 2*H tagged
                                                   float* __restrict__ out) {  // 2*T*H floats
  const int tid = threadIdx.x;
  const int w = tid >> 6;
  const int l = tid & 63;
  const int ublk = blockIdx.x * 8 + 2 * w;  // first of this wave's 2 units

  // Load w_hh into registers. Row r6: gate g = r6>>1, unit = ublk + (r6&1).
  float wreg[6][16];
#pragma unroll
  for (int r6 = 0; r6 < 6; ++r6) {
    const int g = r6 >> 1;
    const int u = ublk + (r6 & 1);
    const float* wrow = whh + (size_t)(g * H + u) * H;
#pragma unroll
    for (int j = 0; j < 16; ++j) wreg[r6][j] = wrow[j * 64 + l];
  }

  const int myu = ublk + l;                       // meaningful for l < 2
  const float bnv = (l < 2) ? bn[myu] : 0.0f;
  const bool gate_lane = (l < 2);

#pragma unroll 1
  for (int t = 0; t < T; ++t) {
    unsigned long long* hb = hbuf + (t & 1) * H;
    unsigned long long* hn = hbuf + ((t + 1) & 1) * H;

    // Early-issue per-unit inputs (off the critical path).
    float ir = 0.f, iz = 0.f, ig = 0.f;
    unsigned long long ph = ~0ull;  // inactive lanes: huge tag, never stale
    if (gate_lane) {
      const float* xpt = xp + (size_t)t * N3;
      ir = xpt[myu];
      iz = xpt[H + myu];
      ig = xpt[2 * H + myu];
      ph = __hip_atomic_load(hb + myu, __ATOMIC_RELAXED, __HIP_MEMORY_SCOPE_AGENT);
    }

    // Phase 1: issue all 16 h loads (one overlapped latency).
    unsigned long long pv[16];
#pragma unroll
    for (int j = 0; j < 16; ++j)
      pv[j] = __hip_atomic_load(hb + j * 64 + l, __ATOMIC_RELAXED, __HIP_MEMORY_SCOPE_AGENT);

    // Phase 2: BATCH re-poll — all stale elements reloaded concurrently.
    while (true) {
      unsigned stale = 0;
#pragma unroll
      for (int j = 0; j < 16; ++j)
        if ((unsigned)(pv[j] >> 32) < (unsigned)t) stale |= (1u << j);
      if (gate_lane && (unsigned)(ph >> 32) < (unsigned)t) stale |= (1u << 16);
      if (!__any(stale != 0)) break;
#pragma unroll
      for (int j = 0; j < 16; ++j)
        if (stale & (1u << j))
          pv[j] = __hip_atomic_load(hb + j * 64 + l, __ATOMIC_RELAXED,
                                    __HIP_MEMORY_SCOPE_AGENT);
      if (stale & (1u << 16))
        ph = __hip_atomic_load(hb + myu, __ATOMIC_RELAXED, __HIP_MEMORY_SCOPE_AGENT);
    }

    float acc[6] = {0.f, 0.f, 0.f, 0.f, 0.f, 0.f};
#pragma unroll
    for (int j = 0; j < 16; ++j) {
      const float hvj = __uint_as_float((unsigned)pv[j]);
#pragma unroll
      for (int r6 = 0; r6 < 6; ++r6) acc[r6] += wreg[r6][j] * hvj;
    }

    // Butterfly reduction over 64 lanes; every lane ends with all 6 sums.
#pragma unroll
    for (int off = 32; off >= 1; off >>= 1) {
#pragma unroll
      for (int r6 = 0; r6 < 6; ++r6) acc[r6] += __shfl_xor(acc[r6], off, 64);
    }

    if (gate_lane) {
      const float hold = __uint_as_float((unsigned)ph);
      // lane l handles unit ublk+l: hr=acc[l], hz=acc[2+l], hg=acc[4+l]
      float r = sigmoidf_fast(ir + acc[l]);
      float z = sigmoidf_fast(iz + acc[2 + l]);
      float gg = tanhf_fast(ig + r * (acc[4 + l] + bnv));
      float hnew = (1.0f - z) * gg + z * hold;
      unsigned long long pk =
          ((unsigned long long)(unsigned)(t + 1) << 32) |
          (unsigned long long)__float_as_uint(hnew);
      __hip_atomic_store(hn + myu, pk, __ATOMIC_RELAXED, __HIP_MEMORY_SCOPE_AGENT);
      out[(size_t)t * H + myu] = hnew;
      out[(size_t)T * H + (size_t)t * H + myu] = hnew;  // second tuple copy
    }
  }
}

// ---------------------------------------------------------------------------
extern "C" void kernel_launch(void* const* d_in, const int* in_sizes, int n_in,
                              void* d_out, int out_size, void* d_ws, size_t ws_size,
                              hipStream_t stream) {
  const float* xs   = (const float*)d_in[0];
  const float* w_ih = (const float*)d_in[1];
  const float* w_hh = (const float*)d_in[2];
  const float* b    = (const float*)d_in[3];
  const float* bn   = (const float*)d_in[4];
  float* out = (float*)d_out;

  // Workspace layout: x_proj (T*3H fp32 = 96MB) | tagged hbuf (2*H u64)
  float* xp = (float*)d_ws;
  unsigned long long* hbuf = (unsigned long long*)(xp + (size_t)T * N3);

  // h0 = 0 with tag 0 (matches step-0 poll); re-done every call inside graph.
  hipMemsetAsync(hbuf, 0, 2 * H * sizeof(unsigned long long), stream);

  dim3 ggrid(N3 / BN, T / BM);
  xproj_gemm<<<ggrid, 256, 0, stream>>>(xs, w_ih, b, xp);

  void* args[] = {(void*)&xp, (void*)&w_hh, (void*)&bn, (void*)&hbuf, (void*)&out};
  hipLaunchCooperativeKernel((void*)gru_scan, dim3(G), dim3(256), args, 0, stream);
}

// Round 4
// 28049.173 us; speedup vs baseline: 4.4402x; 1.1344x over previous
//
#include <hip/hip_runtime.h>
#include <hip/hip_bf16.h>
#include <cstddef>

// Problem constants
constexpr int T = 8192;   // SEQ_LEN
constexpr int H = 1024;   // NHID == NIN
constexpr int N3 = 3 * H; // 3072
constexpr int G = 64;     // scan blocks (cooperative), 512 threads each
constexpr int UPB = 16;   // hidden units per block (G*UPB == H)

// ---------------------------------------------------------------------------
// Kernel 1: x_proj = xs @ w_ih.T + b   (M=8192, N=3072, K=1024, fp32)
// ---------------------------------------------------------------------------
#define BM 64
#define BN 64
#define BK 16
#define PAD 20

__global__ __launch_bounds__(256) void xproj_gemm(const float* __restrict__ A,   // xs [M,K]
                                                  const float* __restrict__ W,   // w_ih [N,K]
                                                  const float* __restrict__ bias,
                                                  float* __restrict__ C) {      // [M,N]
  __shared__ float As[BM * PAD];
  __shared__ float Bs[BN * PAD];
  const int tid = threadIdx.x;
  const int tx = tid & 15;   // N dir
  const int ty = tid >> 4;   // M dir
  const int m0 = blockIdx.y * BM;
  const int n0 = blockIdx.x * BN;

  const int lr = tid >> 2;        // 0..63 row to load
  const int lc = (tid & 3) * 4;   // col offset (float4)

  float acc[4][4] = {};

  for (int k0 = 0; k0 < H; k0 += BK) {
    float4 av = *(const float4*)&A[(size_t)(m0 + lr) * H + k0 + lc];
    float4 bv = *(const float4*)&W[(size_t)(n0 + lr) * H + k0 + lc];
    *(float4*)&As[lr * PAD + lc] = av;
    *(float4*)&Bs[lr * PAD + lc] = bv;
    __syncthreads();
#pragma unroll
    for (int kk = 0; kk < BK; kk += 4) {
      float4 a[4], b[4];
#pragma unroll
      for (int i = 0; i < 4; ++i) a[i] = *(const float4*)&As[(ty * 4 + i) * PAD + kk];
#pragma unroll
      for (int j = 0; j < 4; ++j) b[j] = *(const float4*)&Bs[(tx * 4 + j) * PAD + kk];
#pragma unroll
      for (int i = 0; i < 4; ++i)
#pragma unroll
        for (int j = 0; j < 4; ++j)
          acc[i][j] += a[i].x * b[j].x + a[i].y * b[j].y + a[i].z * b[j].z + a[i].w * b[j].w;
    }
    __syncthreads();
  }

  float4 bb = *(const float4*)&bias[n0 + tx * 4];
#pragma unroll
  for (int i = 0; i < 4; ++i) {
    float4 o;
    o.x = acc[i][0] + bb.x;
    o.y = acc[i][1] + bb.y;
    o.z = acc[i][2] + bb.z;
    o.w = acc[i][3] + bb.w;
    *(float4*)&C[(size_t)(m0 + ty * 4 + i) * N3 + n0 + tx * 4] = o;
  }
}

// ---------------------------------------------------------------------------
// Kernel 2: persistent GRU scan — hierarchical dataflow sync.
//
// h element: u64 {hi: tag = step+1, lo: fp32}, single relaxed agent-scope
// atomic store by the producing gate lane.
//
// Per block (512 thr = 8 waves, 2 units/wave): ONLY WAVE 0 polls the global
// tagged h (16 loads, batch re-poll), then broadcasts values via LDS; one
// __syncthreads; all waves gather h from LDS and compute. This cuts global
// pollers 8x (512 -> 64) vs R3 — attacking same-line reader contention at
// the coherence point.
//
// No second barrier: wave0 overwrites lds_h only after its NEXT poll
// completes, which requires all blocks (incl. its own waves) to have stored
// h_{t+1}, which they do only after finishing their LDS reads of h_t.
// Double-buffer safety: a producer overwrites the h_t slot (with h_{t+2})
// only after consuming all of h_{t+1}, implying everyone finished step t.
// ---------------------------------------------------------------------------
__device__ __forceinline__ float sigmoidf_fast(float x) {
  return 1.0f / (1.0f + __expf(-x));
}
__device__ __forceinline__ float tanhf_fast(float x) {
  float ax = fabsf(x);
  float e = __expf(-2.0f * ax);      // e <= 1, always stable
  float t = (1.0f - e) / (1.0f + e);
  return copysignf(t, x);
}

__global__ __launch_bounds__(512, 1) void gru_scan(const float* __restrict__ xp,
                                                   const float* __restrict__ whh,
                                                   const float* __restrict__ bn,
                                                   unsigned long long* __restrict__ hbuf, // 2*H tagged
                                                   float* __restrict__ out) {  // 2*T*H floats
  __shared__ float lds_h[H];  // broadcast buffer for current h_t

  const int tid = threadIdx.x;
  const int w = tid >> 6;    // wave 0..7
  const int l = tid & 63;
  const int ublk = blockIdx.x * UPB + 2 * w;  // first of this wave's 2 units

  // Load w_hh into registers. Row r6: gate g = r6>>1, unit = ublk + (r6&1).
  // Lane l holds elements k = j*64 + l.
  float wreg[6][16];
#pragma unroll
  for (int r6 = 0; r6 < 6; ++r6) {
    const int g = r6 >> 1;
    const int u = ublk + (r6 & 1);
    const float* wrow = whh + (size_t)(g * H + u) * H;
#pragma unroll
    for (int j = 0; j < 16; ++j) wreg[r6][j] = wrow[j * 64 + l];
  }

  const int myu = ublk + l;                       // meaningful for l < 2
  const float bnv = (l < 2) ? bn[myu] : 0.0f;
  const bool gate_lane = (l < 2);

#pragma unroll 1
  for (int t = 0; t < T; ++t) {
    unsigned long long* hb = hbuf + (t & 1) * H;
    unsigned long long* hn = hbuf + ((t + 1) & 1) * H;

    // Early-issue per-unit xp inputs; latency hides under barrier wait.
    float ir = 0.f, iz = 0.f, ig = 0.f;
    if (gate_lane) {
      const float* xpt = xp + (size_t)t * N3;
      ir = xpt[myu];
      iz = xpt[H + myu];
      ig = xpt[2 * H + myu];
    }

    if (w == 0) {
      // Wave 0: gather the full tagged h, batch re-poll, broadcast via LDS.
      unsigned long long pv[16];
#pragma unroll
      for (int j = 0; j < 16; ++j)
        pv[j] = __hip_atomic_load(hb + j * 64 + l, __ATOMIC_RELAXED,
                                  __HIP_MEMORY_SCOPE_AGENT);
      while (true) {
        unsigned stale = 0;
#pragma unroll
        for (int j = 0; j < 16; ++j)
          if ((unsigned)(pv[j] >> 32) < (unsigned)t) stale |= (1u << j);
        if (!__any(stale != 0)) break;
#pragma unroll
        for (int j = 0; j < 16; ++j)
          if (stale & (1u << j))
            pv[j] = __hip_atomic_load(hb + j * 64 + l, __ATOMIC_RELAXED,
                                      __HIP_MEMORY_SCOPE_AGENT);
      }
#pragma unroll
      for (int j = 0; j < 16; ++j)
        lds_h[j * 64 + l] = __uint_as_float((unsigned)pv[j]);
    }
    __syncthreads();  // releases fresh lds_h to all waves

    // All waves: gather h from LDS (lane l reads k = j*64+l; 2-way alias, free).
    float hv[16];
#pragma unroll
    for (int j = 0; j < 16; ++j) hv[j] = lds_h[j * 64 + l];

    float acc[6] = {0.f, 0.f, 0.f, 0.f, 0.f, 0.f};
#pragma unroll
    for (int j = 0; j < 16; ++j) {
#pragma unroll
      for (int r6 = 0; r6 < 6; ++r6) acc[r6] += wreg[r6][j] * hv[j];
    }

    // Butterfly reduction over 64 lanes; every lane ends with all 6 sums.
#pragma unroll
    for (int off = 32; off >= 1; off >>= 1) {
#pragma unroll
      for (int r6 = 0; r6 < 6; ++r6) acc[r6] += __shfl_xor(acc[r6], off, 64);
    }

    if (gate_lane) {
      const float hold = lds_h[myu];  // h_t for this unit, free from LDS
      // lane l handles unit ublk+l: hr=acc[l], hz=acc[2+l], hg=acc[4+l]
      float r = sigmoidf_fast(ir + acc[l]);
      float z = sigmoidf_fast(iz + acc[2 + l]);
      float gg = tanhf_fast(ig + r * (acc[4 + l] + bnv));
      float hnew = (1.0f - z) * gg + z * hold;
      unsigned long long pk =
          ((unsigned long long)(unsigned)(t + 1) << 32) |
          (unsigned long long)__float_as_uint(hnew);
      __hip_atomic_store(hn + myu, pk, __ATOMIC_RELAXED, __HIP_MEMORY_SCOPE_AGENT);
      out[(size_t)t * H + myu] = hnew;
      out[(size_t)T * H + (size_t)t * H + myu] = hnew;  // second tuple copy
    }
  }
}

// ---------------------------------------------------------------------------
extern "C" void kernel_launch(void* const* d_in, const int* in_sizes, int n_in,
                              void* d_out, int out_size, void* d_ws, size_t ws_size,
                              hipStream_t stream) {
  const float* xs   = (const float*)d_in[0];
  const float* w_ih = (const float*)d_in[1];
  const float* w_hh = (const float*)d_in[2];
  const float* b    = (const float*)d_in[3];
  const float* bn   = (const float*)d_in[4];
  float* out = (float*)d_out;

  // Workspace layout: x_proj (T*3H fp32 = 96MB) | tagged hbuf (2*H u64)
  float* xp = (float*)d_ws;
  unsigned long long* hbuf = (unsigned long long*)(xp + (size_t)T * N3);

  // h0 = 0 with tag 0 (matches step-0 poll); re-done every call inside graph.
  hipMemsetAsync(hbuf, 0, 2 * H * sizeof(unsigned long long), stream);

  dim3 ggrid(N3 / BN, T / BM);
  xproj_gemm<<<ggrid, 256, 0, stream>>>(xs, w_ih, b, xp);

  void* args[] = {(void*)&xp, (void*)&w_hh, (void*)&bn, (void*)&hbuf, (void*)&out};
  hipLaunchCooperativeKernel((void*)gru_scan, dim3(G), dim3(512), args, 0, stream);
}